// Round 9
// baseline (420.613 us; speedup 1.0000x reference)
//
#include <hip/hip_runtime.h>
#include <math.h>

// NLL of a Gaussian mixed model via double Schur complement / Woodbury.
// N=4096, factors Q0=1000, Q1=500. The N x N solve reduces to a 500x500
// (padded 512) Cholesky with the RHS appended as row 500 (augmented-row
// trick: z^T z = KAPPA - L[500][500]^2, logdet from diag of L).
// S is assembled SPARSELY by pair-enumeration over points grouped by z0.
// 3 launches total: memset + k_pre (scatter/scan/sort, 16 blocks) +
// k_chol (init + assemble + persistent blocked Cholesky, 28 blocks).
// Grid barriers poll with relaxed atomic LOADS (no RMW contention).

constexpr int N_PTS = 4096;
constexpr int Q0 = 1000;
constexpr int Q1 = 500;
constexpr int QP = 512;
constexpr float LOG_2PI = 1.8378770664093453f;
constexpr float KAPPA = 16384.f;   // > z^T z (~<= r^T r ~ 8200)

// ---- workspace layout (float offsets) ----
constexpr int OFF_C0   = 0;        // counts factor 0 [1000]
constexpr int OFF_C1   = 1024;     // counts factor 1 [500]
constexpr int OFF_U0   = 2048;     // residual sums factor 0 [1000]
constexpr int OFF_U1   = 3072;     // residual sums factor 1 [500]
constexpr int OFF_SC   = 3584;     // [0]=r^T r [1]=sum log a [2]=u0^T A^-1 u0
constexpr int OFF_BARP = 3616;     // k_pre barrier counter (own cacheline)
constexpr int OFF_BARC = 3648;     // k_chol barrier counter (own cacheline)
constexpr int ZERO_FLOATS = 3680;  // memset range
constexpr int OFF_INVD = 3712;     // inv diag of L [512] (fully written before read)
constexpr int OFF_OFFS = 4608;     // int[1024] exclusive offsets of sorted groups
constexpr int OFF_CURS = 5632;     // int[1024] scatter cursors
constexpr int OFF_SRT  = 6656;     // int[4096] z1 of points sorted by z0
constexpr int OFF_S    = 12288;    // S [QP][QP]
constexpr int NB_PRE   = 16;
constexpr int NB_CHOL  = 28;

__device__ __forceinline__ float readlane_f(float v, int l) {
    return __int_as_float(__builtin_amdgcn_readlane(__float_as_int(v), l));
}

// grid barrier: RMW once to arrive, then poll with relaxed LOADs only.
__device__ __forceinline__ void gbar(unsigned* cnt, int* it, int nb) {
    __syncthreads();
    if (threadIdx.x == 0) {
        __threadfence();   // release
        __hip_atomic_fetch_add(cnt, 1u, __ATOMIC_RELAXED, __HIP_MEMORY_SCOPE_AGENT);
        unsigned target = (unsigned)nb * (unsigned)(++(*it));
        while (__hip_atomic_load(cnt, __ATOMIC_RELAXED, __HIP_MEMORY_SCOPE_AGENT) < target)
            __builtin_amdgcn_s_sleep(8);
        __threadfence();   // acquire
    }
    __syncthreads();
}

// ------------------------------------------------------------------
// k_pre: scatter -> prefix scan -> counting sort (16 blocks)
// ------------------------------------------------------------------
__global__ __launch_bounds__(256) void k_pre(const float* __restrict__ yt,
                                             const float* __restrict__ yp,
                                             const int* __restrict__ z0,
                                             const int* __restrict__ z1,
                                             float* __restrict__ ws) {
    unsigned* bar = (unsigned*)(ws + OFF_BARP);
    int it = 0;
    const int tid = threadIdx.x;
    const int i = blockIdx.x * 256 + tid;     // exactly 4096 threads

    // phase A: scatter
    float r = yt[i] - yp[i];
    int i0 = z0[i];
    int i1 = z1[i];
    atomicAdd(&ws[OFF_C0 + i0], 1.0f);
    atomicAdd(&ws[OFF_C1 + i1], 1.0f);
    atomicAdd(&ws[OFF_U0 + i0], r);
    atomicAdd(&ws[OFF_U1 + i1], r);
    float r2 = r * r;
    #pragma unroll
    for (int off = 32; off; off >>= 1) r2 += __shfl_down(r2, off, 64);
    if ((tid & 63) == 0) atomicAdd(&ws[OFF_SC + 0], r2);

    gbar(bar, &it, NB_PRE);

    // phase B: block 0 scans C0 -> OFFS/CURS (1024 entries, 4 per thread)
    if (blockIdx.x == 0) {
        __shared__ int sums[256];
        int b4 = tid * 4;
        int v[4], tot = 0;
        #pragma unroll
        for (int k = 0; k < 4; ++k) {
            v[k] = (b4 + k < Q0) ? (int)ws[OFF_C0 + b4 + k] : 0;
            tot += v[k];
        }
        sums[tid] = tot;
        __syncthreads();
        for (int off = 1; off < 256; off <<= 1) {
            int a = (tid >= off) ? sums[tid - off] : 0;
            __syncthreads();
            sums[tid] += a;
            __syncthreads();
        }
        int run = sums[tid] - tot;    // exclusive base
        int* offs = (int*)(ws + OFF_OFFS);
        int* curs = (int*)(ws + OFF_CURS);
        #pragma unroll
        for (int k = 0; k < 4; ++k) {
            offs[b4 + k] = run;
            curs[b4 + k] = run;
            run += v[k];
        }
    }

    gbar(bar, &it, NB_PRE);

    // phase C: counting-sort scatter of z1 grouped by z0
    int slot = atomicAdd(&((int*)(ws + OFF_CURS))[i0], 1);
    ((int*)(ws + OFF_SRT))[slot] = i1;
}

// ------------------------------------------------------------------
// register Cholesky of a 64x64 block (lane = row), masked store,
// plus reciprocal-diagonal store
// ------------------------------------------------------------------
__device__ __forceinline__ void chol64_store(float (&d)[64], float* S, float* invd,
                                             int base, int lane) {
    float myinv = 0.f;
    #pragma unroll
    for (int j = 0; j < 64; ++j) {
        float diag = readlane_f(d[j], j);
        float rs = rsqrtf(diag);
        if (lane == j) myinv = rs;
        d[j] *= rs;
        float lj = d[j];
        #pragma unroll
        for (int k = j + 1; k < 64; ++k)
            d[k] = fmaf(-lj, readlane_f(lj, k), d[k]);
    }
    invd[base + lane] = myinv;     // 1/L[j][j], exact rsqrt approx (<=1ulp)
    float* wr = S + (size_t)(base + lane) * QP + base;
    #pragma unroll
    for (int c = 0; c < 16; ++c) {
        float4 v;
        v.x = (4 * c + 0 <= lane) ? d[4 * c + 0] : 0.f;
        v.y = (4 * c + 1 <= lane) ? d[4 * c + 1] : 0.f;
        v.z = (4 * c + 2 <= lane) ? d[4 * c + 2] : 0.f;
        v.w = (4 * c + 3 <= lane) ? d[4 * c + 3] : 0.f;
        *reinterpret_cast<float4*>(wr + 4 * c) = v;
    }
}

// triangular solve of 64 panel rows (lane = row) against factored D at x;
// division-free (uses invd); result into LDS tile
__device__ __forceinline__ void solve_tile(const float* S, const float* invd,
                                           int x, int g0, float (*out)[65], int lane) {
    float invv = invd[x + lane];
    float dreg[64], p[64];
    const float* dr = S + (size_t)(x + lane) * QP + x;
    const float* pr = S + (size_t)(g0 + lane) * QP + x;
    #pragma unroll
    for (int c = 0; c < 16; ++c) {
        float4 v = *reinterpret_cast<const float4*>(dr + 4 * c);
        dreg[4 * c] = v.x; dreg[4 * c + 1] = v.y; dreg[4 * c + 2] = v.z; dreg[4 * c + 3] = v.w;
        float4 q = *reinterpret_cast<const float4*>(pr + 4 * c);
        p[4 * c] = q.x; p[4 * c + 1] = q.y; p[4 * c + 2] = q.z; p[4 * c + 3] = q.w;
    }
    #pragma unroll
    for (int j = 0; j < 64; ++j) {
        float pj = p[j] * readlane_f(invv, j);
        p[j] = pj;
        #pragma unroll
        for (int k = j + 1; k < 64; ++k)
            p[k] = fmaf(-pj, readlane_f(dreg[j], k), p[k]);
    }
    #pragma unroll
    for (int k = 0; k < 64; ++k) out[lane][k] = p[k];
}

// ------------------------------------------------------------------
// k_chol: init S + sparse assembly + persistent blocked Cholesky + epilogue
// ------------------------------------------------------------------
__global__ __launch_bounds__(256) void k_chol(const float* __restrict__ sig2e,
                                              const float* __restrict__ sig2bs,
                                              float* __restrict__ ws,
                                              float* __restrict__ out) {
    float* S = ws + OFF_S;
    float* invd = ws + OFF_INVD;
    unsigned* bar = (unsigned*)(ws + OFF_BARC);
    const int tid = threadIdx.x;
    const int lane = tid & 63;
    const int w = tid >> 6;
    const int blk = blockIdx.x;
    __shared__ float Pi[64][65];
    __shared__ float Pj[64][65];
    int bit = 0;

    const float se = sig2e[0], sb0 = sig2bs[0], sb1 = sig2bs[1];
    const float inv_se = 1.f / se, inv_sb0 = 1.f / sb0, inv_sb1 = 1.f / sb1;

    // ---- phase 0a: init S base (diag, rhs row 500, identity padding) ----
    {
        const float* C1w = ws + OFF_C1;
        const float* U1w = ws + OFF_U1;
        for (int e = blk * 256 + tid; e < QP * QP / 4; e += NB_CHOL * 256) {
            int i = e >> 7;
            int j0 = (e & 127) << 2;
            float4 v;
            float* el = &v.x;
            #pragma unroll
            for (int t = 0; t < 4; ++t) {
                int j = j0 + t;
                float x = 0.f;
                if (i == 500)      x = (j < Q1) ? U1w[j] : ((j == 500) ? KAPPA : 0.f);
                else if (i == j)   x = (i < Q1) ? (inv_sb1 + C1w[i] * inv_se) : 1.f;
                el[t] = x;
            }
            *reinterpret_cast<float4*>(S + (size_t)i * QP + j0) = v;
        }
    }
    gbar(bar, &bit, NB_CHOL);

    // ---- phase 0b: sparse pair assembly (thread per group g0) ----
    {
        int g = blk * 256 + tid;
        if (g < Q0) {
            const int* offs = (const int*)(ws + OFF_OFFS);
            const int* srt  = (const int*)(ws + OFF_SRT);
            float cg = ws[OFF_C0 + g];
            float a  = inv_sb0 + cg * inv_se;
            float u0 = ws[OFF_U0 + g];
            float wu = u0 / a;
            atomicAdd(&ws[OFF_SC + 1], logf(a));
            atomicAdd(&ws[OFF_SC + 2], u0 * wu);
            int beg = offs[g];
            int cnt = (int)cg;
            float coef = -inv_se * inv_se / a;
            float rhsv = -inv_se * wu;
            for (int ia = beg; ia < beg + cnt; ++ia) {
                int ca = srt[ia];
                atomicAdd(&S[(size_t)500 * QP + ca], rhsv);
                for (int ib = beg; ib < beg + cnt; ++ib) {
                    int cb = srt[ib];
                    if (ca >= cb) atomicAdd(&S[(size_t)ca * QP + cb], coef);
                }
            }
        }
    }
    gbar(bar, &bit, NB_CHOL);

    // ---- phase 0c: block 0 factors D0 ----
    if (blk == 0 && w == 0) {
        float d[64];
        const float* row = S + (size_t)lane * QP;
        #pragma unroll
        for (int c = 0; c < 16; ++c) {
            float4 v = *reinterpret_cast<const float4*>(row + 4 * c);
            d[4 * c] = v.x; d[4 * c + 1] = v.y; d[4 * c + 2] = v.z; d[4 * c + 3] = v.w;
        }
        chol64_store(d, S, invd, 0, lane);
    }
    gbar(bar, &bit, NB_CHOL);

    // ---- main factorization: 7 steps ----
    for (int s = 0; s < 7; ++s) {
        const int x = 64 * s;
        const int T = 7 - s;
        const int nt = T * (T + 1) / 2;
        if (blk < nt) {
            int ti = 0;
            while ((ti + 1) * (ti + 2) / 2 <= blk) ++ti;
            int tj = blk - ti * (ti + 1) / 2;
            const int gi0 = x + 64 + 64 * ti;
            const int gj0 = x + 64 + 64 * tj;

            // redundant panel solves, straight into LDS
            if (w == 0)                     solve_tile(S, invd, x, gi0, Pi, lane);
            else if (w == 1 && ti != tj)    solve_tile(S, invd, x, gj0, Pj, lane);
            __syncthreads();

            // SYRK update of the trailing tile
            float (*PJ)[65] = (ti == tj) ? Pi : Pj;
            const int ta = tid >> 4, tb = tid & 15;
            float acc[4][4] = {{0.f}};
            #pragma unroll
            for (int j = 0; j < 64; ++j) {
                float pa[4], pb[4];
                #pragma unroll
                for (int u = 0; u < 4; ++u) { pa[u] = Pi[ta * 4 + u][j]; pb[u] = PJ[tb * 4 + u][j]; }
                #pragma unroll
                for (int u = 0; u < 4; ++u)
                    #pragma unroll
                    for (int v = 0; v < 4; ++v) acc[u][v] += pa[u] * pb[v];
            }

            if (ti > tj) {
                #pragma unroll
                for (int u = 0; u < 4; ++u) {
                    float4* ptr = (float4*)&S[(size_t)(gi0 + ta * 4 + u) * QP + gj0 + tb * 4];
                    float4 cv = *ptr;
                    cv.x -= acc[u][0]; cv.y -= acc[u][1]; cv.z -= acc[u][2]; cv.w -= acc[u][3];
                    *ptr = cv;
                }
            } else {
                float nv[4][4];
                #pragma unroll
                for (int u = 0; u < 4; ++u) {
                    float4 cv = *(const float4*)&S[(size_t)(gi0 + ta * 4 + u) * QP + gj0 + tb * 4];
                    nv[u][0] = cv.x - acc[u][0]; nv[u][1] = cv.y - acc[u][1];
                    nv[u][2] = cv.z - acc[u][2]; nv[u][3] = cv.w - acc[u][3];
                }
                #pragma unroll
                for (int u = 0; u < 4; ++u)
                    #pragma unroll
                    for (int v = 0; v < 4; ++v) {
                        int gi = gi0 + ta * 4 + u, gj = gj0 + tb * 4 + v;
                        if (gi >= gj) S[(size_t)gi * QP + gj] = nv[u][v];
                    }
                if (ti == 0) {   // stage full updated tile for in-step factor
                    #pragma unroll
                    for (int u = 0; u < 4; ++u)
                        #pragma unroll
                        for (int v = 0; v < 4; ++v)
                            Pj[ta * 4 + u][tb * 4 + v] = nv[u][v];
                }
            }

            // block 0 == tile (0,0): factor next diagonal block in-step
            if (blk == 0) {
                __syncthreads();
                if (w == 0) {
                    float d[64];
                    #pragma unroll
                    for (int k = 0; k < 64; ++k) d[k] = Pj[lane][k];
                    chol64_store(d, S, invd, x + 64, lane);
                }
            }
        }
        gbar(bar, &bit, NB_CHOL);
    }

    // ---- epilogue: block 0 reduces logdet + combines scalars ----
    if (blk == 0) {
        float ld = 0.f;
        for (int i = tid; i < Q1; i += 256) ld += logf(S[(size_t)i * QP + i]);
        float* red = &Pi[0][0];
        __syncthreads();
        red[tid] = ld;
        __syncthreads();
        if (tid < 128) red[tid] += red[tid + 128];
        __syncthreads();
        if (tid < 64) red[tid] += red[tid + 64];
        __syncthreads();
        if (tid < 64) {
            float v = red[tid];
            #pragma unroll
            for (int o = 32; o; o >>= 1) v += __shfl_down(v, o, 64);
            if (tid == 0) {
                float L55 = S[(size_t)500 * QP + 500];
                float zz = KAPPA - L55 * L55;          // z^T z = v^T S^-1 v
                float rtr = ws[OFF_SC + 0];
                float la  = ws[OFF_SC + 1];
                float q0p = ws[OFF_SC + 2];
                float umu = q0p + zz;                  // u^T M^-1 u
                float loss2 = inv_se * rtr - inv_se * inv_se * umu;
                float logdetV = (float)N_PTS * logf(se)
                              + (float)Q0 * logf(sb0)
                              + (float)Q1 * logf(sb1)
                              + la + 2.f * v;
                out[0] = 0.5f * ((float)N_PTS * LOG_2PI + logdetV + loss2);
            }
        }
    }
}

// ------------------------------------------------------------------
extern "C" void kernel_launch(void* const* d_in, const int* in_sizes, int n_in,
                              void* d_out, int out_size, void* d_ws, size_t ws_size,
                              hipStream_t stream) {
    const float* yt = (const float*)d_in[0];
    const float* yp = (const float*)d_in[1];
    const int*   z0 = (const int*)d_in[2];
    const int*   z1 = (const int*)d_in[3];
    const float* se = (const float*)d_in[4];
    const float* sb = (const float*)d_in[5];
    float* ws  = (float*)d_ws;
    float* out = (float*)d_out;

    hipMemsetAsync(d_ws, 0, (size_t)ZERO_FLOATS * sizeof(float), stream);
    hipLaunchKernelGGL(k_pre, dim3(NB_PRE), dim3(256), 0, stream, yt, yp, z0, z1, ws);
    hipLaunchKernelGGL(k_chol, dim3(NB_CHOL), dim3(256), 0, stream, se, sb, ws, out);
}

// Round 10
// 417.899 us; speedup vs baseline: 1.0065x; 1.0065x over previous
//
#include <hip/hip_runtime.h>
#include <math.h>

// NLL of a Gaussian mixed model via double Schur complement / Woodbury.
// N=4096, factors Q0=1000, Q1=500. The N x N solve reduces to a 500x500
// (padded 512) Cholesky with the RHS appended as row 500 (augmented-row
// trick: z^T z = KAPPA - L[500][500]^2, logdet from diag of L).
// S is assembled SPARSELY by pair-enumeration over points grouped by z0.
// 3 launches total: memset + k_pre (scatter/scan/sort, 16 blocks) +
// k_chol (init + assemble + persistent blocked Cholesky, 28 blocks).
//
// ROUND-10 FIX: k_chol is __launch_bounds__(256, 1). Without the min-waves
// arg the compiler allocated only 84 VGPRs and spilled dreg[64]/p[64]/d[64]
// to scratch -- every readlane chain became a serial scratch-reload chain
// (VALUBusy 0.45%, WRITE_SIZE ~2.8MB of spill stores). (256,1) gives the
// allocator the full per-wave budget; 28 blocks = 1/CU so occupancy is moot.

constexpr int N_PTS = 4096;
constexpr int Q0 = 1000;
constexpr int Q1 = 500;
constexpr int QP = 512;
constexpr float LOG_2PI = 1.8378770664093453f;
constexpr float KAPPA = 16384.f;   // > z^T z (~<= r^T r ~ 8200)

// ---- workspace layout (float offsets) ----
constexpr int OFF_C0   = 0;        // counts factor 0 [1000]
constexpr int OFF_C1   = 1024;     // counts factor 1 [500]
constexpr int OFF_U0   = 2048;     // residual sums factor 0 [1000]
constexpr int OFF_U1   = 3072;     // residual sums factor 1 [500]
constexpr int OFF_SC   = 3584;     // [0]=r^T r [1]=sum log a [2]=u0^T A^-1 u0
constexpr int OFF_BARP = 3616;     // k_pre barrier counter (own cacheline)
constexpr int OFF_BARC = 3648;     // k_chol barrier counter (own cacheline)
constexpr int ZERO_FLOATS = 3680;  // memset range
constexpr int OFF_INVD = 3712;     // inv diag of L [512] (fully written before read)
constexpr int OFF_OFFS = 4608;     // int[1024] exclusive offsets of sorted groups
constexpr int OFF_CURS = 5632;     // int[1024] scatter cursors
constexpr int OFF_SRT  = 6656;     // int[4096] z1 of points sorted by z0
constexpr int OFF_S    = 12288;    // S [QP][QP]
constexpr int NB_PRE   = 16;
constexpr int NB_CHOL  = 28;

__device__ __forceinline__ float readlane_f(float v, int l) {
    return __int_as_float(__builtin_amdgcn_readlane(__float_as_int(v), l));
}

// grid barrier: RMW once to arrive, then poll with relaxed LOADs only.
__device__ __forceinline__ void gbar(unsigned* cnt, int* it, int nb) {
    __syncthreads();
    if (threadIdx.x == 0) {
        __threadfence();   // release
        __hip_atomic_fetch_add(cnt, 1u, __ATOMIC_RELAXED, __HIP_MEMORY_SCOPE_AGENT);
        unsigned target = (unsigned)nb * (unsigned)(++(*it));
        while (__hip_atomic_load(cnt, __ATOMIC_RELAXED, __HIP_MEMORY_SCOPE_AGENT) < target)
            __builtin_amdgcn_s_sleep(8);
        __threadfence();   // acquire
    }
    __syncthreads();
}

// ------------------------------------------------------------------
// k_pre: scatter -> prefix scan -> counting sort (16 blocks)
// ------------------------------------------------------------------
__global__ __launch_bounds__(256) void k_pre(const float* __restrict__ yt,
                                             const float* __restrict__ yp,
                                             const int* __restrict__ z0,
                                             const int* __restrict__ z1,
                                             float* __restrict__ ws) {
    unsigned* bar = (unsigned*)(ws + OFF_BARP);
    int it = 0;
    const int tid = threadIdx.x;
    const int i = blockIdx.x * 256 + tid;     // exactly 4096 threads

    // phase A: scatter
    float r = yt[i] - yp[i];
    int i0 = z0[i];
    int i1 = z1[i];
    atomicAdd(&ws[OFF_C0 + i0], 1.0f);
    atomicAdd(&ws[OFF_C1 + i1], 1.0f);
    atomicAdd(&ws[OFF_U0 + i0], r);
    atomicAdd(&ws[OFF_U1 + i1], r);
    float r2 = r * r;
    #pragma unroll
    for (int off = 32; off; off >>= 1) r2 += __shfl_down(r2, off, 64);
    if ((tid & 63) == 0) atomicAdd(&ws[OFF_SC + 0], r2);

    gbar(bar, &it, NB_PRE);

    // phase B: block 0 scans C0 -> OFFS/CURS (1024 entries, 4 per thread)
    if (blockIdx.x == 0) {
        __shared__ int sums[256];
        int b4 = tid * 4;
        int v[4], tot = 0;
        #pragma unroll
        for (int k = 0; k < 4; ++k) {
            v[k] = (b4 + k < Q0) ? (int)ws[OFF_C0 + b4 + k] : 0;
            tot += v[k];
        }
        sums[tid] = tot;
        __syncthreads();
        for (int off = 1; off < 256; off <<= 1) {
            int a = (tid >= off) ? sums[tid - off] : 0;
            __syncthreads();
            sums[tid] += a;
            __syncthreads();
        }
        int run = sums[tid] - tot;    // exclusive base
        int* offs = (int*)(ws + OFF_OFFS);
        int* curs = (int*)(ws + OFF_CURS);
        #pragma unroll
        for (int k = 0; k < 4; ++k) {
            offs[b4 + k] = run;
            curs[b4 + k] = run;
            run += v[k];
        }
    }

    gbar(bar, &it, NB_PRE);

    // phase C: counting-sort scatter of z1 grouped by z0
    int slot = atomicAdd(&((int*)(ws + OFF_CURS))[i0], 1);
    ((int*)(ws + OFF_SRT))[slot] = i1;
}

// ------------------------------------------------------------------
// register Cholesky of a 64x64 block (lane = row), masked store,
// plus reciprocal-diagonal store
// ------------------------------------------------------------------
__device__ __forceinline__ void chol64_store(float (&d)[64], float* S, float* invd,
                                             int base, int lane) {
    float myinv = 0.f;
    #pragma unroll
    for (int j = 0; j < 64; ++j) {
        float diag = readlane_f(d[j], j);
        float rs = rsqrtf(diag);
        if (lane == j) myinv = rs;
        d[j] *= rs;
        float lj = d[j];
        #pragma unroll
        for (int k = j + 1; k < 64; ++k)
            d[k] = fmaf(-lj, readlane_f(lj, k), d[k]);
    }
    invd[base + lane] = myinv;     // 1/L[j][j], exact rsqrt approx (<=1ulp)
    float* wr = S + (size_t)(base + lane) * QP + base;
    #pragma unroll
    for (int c = 0; c < 16; ++c) {
        float4 v;
        v.x = (4 * c + 0 <= lane) ? d[4 * c + 0] : 0.f;
        v.y = (4 * c + 1 <= lane) ? d[4 * c + 1] : 0.f;
        v.z = (4 * c + 2 <= lane) ? d[4 * c + 2] : 0.f;
        v.w = (4 * c + 3 <= lane) ? d[4 * c + 3] : 0.f;
        *reinterpret_cast<float4*>(wr + 4 * c) = v;
    }
}

// triangular solve of 64 panel rows (lane = row) against factored D at x;
// division-free (uses invd); result into LDS tile
__device__ __forceinline__ void solve_tile(const float* S, const float* invd,
                                           int x, int g0, float (*out)[65], int lane) {
    float invv = invd[x + lane];
    float dreg[64], p[64];
    const float* dr = S + (size_t)(x + lane) * QP + x;
    const float* pr = S + (size_t)(g0 + lane) * QP + x;
    #pragma unroll
    for (int c = 0; c < 16; ++c) {
        float4 v = *reinterpret_cast<const float4*>(dr + 4 * c);
        dreg[4 * c] = v.x; dreg[4 * c + 1] = v.y; dreg[4 * c + 2] = v.z; dreg[4 * c + 3] = v.w;
        float4 q = *reinterpret_cast<const float4*>(pr + 4 * c);
        p[4 * c] = q.x; p[4 * c + 1] = q.y; p[4 * c + 2] = q.z; p[4 * c + 3] = q.w;
    }
    #pragma unroll
    for (int j = 0; j < 64; ++j) {
        float pj = p[j] * readlane_f(invv, j);
        p[j] = pj;
        #pragma unroll
        for (int k = j + 1; k < 64; ++k)
            p[k] = fmaf(-pj, readlane_f(dreg[j], k), p[k]);
    }
    #pragma unroll
    for (int k = 0; k < 64; ++k) out[lane][k] = p[k];
}

// ------------------------------------------------------------------
// k_chol: init S + sparse assembly + persistent blocked Cholesky + epilogue
// ------------------------------------------------------------------
__global__ __launch_bounds__(256, 1) void k_chol(const float* __restrict__ sig2e,
                                                 const float* __restrict__ sig2bs,
                                                 float* __restrict__ ws,
                                                 float* __restrict__ out) {
    float* S = ws + OFF_S;
    float* invd = ws + OFF_INVD;
    unsigned* bar = (unsigned*)(ws + OFF_BARC);
    const int tid = threadIdx.x;
    const int lane = tid & 63;
    const int w = tid >> 6;
    const int blk = blockIdx.x;
    __shared__ float Pi[64][65];
    __shared__ float Pj[64][65];
    int bit = 0;

    const float se = sig2e[0], sb0 = sig2bs[0], sb1 = sig2bs[1];
    const float inv_se = 1.f / se, inv_sb0 = 1.f / sb0, inv_sb1 = 1.f / sb1;

    // ---- phase 0a: init S base (diag, rhs row 500, identity padding) ----
    {
        const float* C1w = ws + OFF_C1;
        const float* U1w = ws + OFF_U1;
        for (int e = blk * 256 + tid; e < QP * QP / 4; e += NB_CHOL * 256) {
            int i = e >> 7;
            int j0 = (e & 127) << 2;
            float4 v;
            float* el = &v.x;
            #pragma unroll
            for (int t = 0; t < 4; ++t) {
                int j = j0 + t;
                float x = 0.f;
                if (i == 500)      x = (j < Q1) ? U1w[j] : ((j == 500) ? KAPPA : 0.f);
                else if (i == j)   x = (i < Q1) ? (inv_sb1 + C1w[i] * inv_se) : 1.f;
                el[t] = x;
            }
            *reinterpret_cast<float4*>(S + (size_t)i * QP + j0) = v;
        }
    }
    gbar(bar, &bit, NB_CHOL);

    // ---- phase 0b: sparse pair assembly (thread per group g0) ----
    {
        int g = blk * 256 + tid;
        if (g < Q0) {
            const int* offs = (const int*)(ws + OFF_OFFS);
            const int* srt  = (const int*)(ws + OFF_SRT);
            float cg = ws[OFF_C0 + g];
            float a  = inv_sb0 + cg * inv_se;
            float u0 = ws[OFF_U0 + g];
            float wu = u0 / a;
            atomicAdd(&ws[OFF_SC + 1], logf(a));
            atomicAdd(&ws[OFF_SC + 2], u0 * wu);
            int beg = offs[g];
            int cnt = (int)cg;
            float coef = -inv_se * inv_se / a;
            float rhsv = -inv_se * wu;
            for (int ia = beg; ia < beg + cnt; ++ia) {
                int ca = srt[ia];
                atomicAdd(&S[(size_t)500 * QP + ca], rhsv);
                for (int ib = beg; ib < beg + cnt; ++ib) {
                    int cb = srt[ib];
                    if (ca >= cb) atomicAdd(&S[(size_t)ca * QP + cb], coef);
                }
            }
        }
    }
    gbar(bar, &bit, NB_CHOL);

    // ---- phase 0c: block 0 factors D0 ----
    if (blk == 0 && w == 0) {
        float d[64];
        const float* row = S + (size_t)lane * QP;
        #pragma unroll
        for (int c = 0; c < 16; ++c) {
            float4 v = *reinterpret_cast<const float4*>(row + 4 * c);
            d[4 * c] = v.x; d[4 * c + 1] = v.y; d[4 * c + 2] = v.z; d[4 * c + 3] = v.w;
        }
        chol64_store(d, S, invd, 0, lane);
    }
    gbar(bar, &bit, NB_CHOL);

    // ---- main factorization: 7 steps ----
    for (int s = 0; s < 7; ++s) {
        const int x = 64 * s;
        const int T = 7 - s;
        const int nt = T * (T + 1) / 2;
        if (blk < nt) {
            int ti = 0;
            while ((ti + 1) * (ti + 2) / 2 <= blk) ++ti;
            int tj = blk - ti * (ti + 1) / 2;
            const int gi0 = x + 64 + 64 * ti;
            const int gj0 = x + 64 + 64 * tj;

            // redundant panel solves, straight into LDS
            if (w == 0)                     solve_tile(S, invd, x, gi0, Pi, lane);
            else if (w == 1 && ti != tj)    solve_tile(S, invd, x, gj0, Pj, lane);
            __syncthreads();

            // SYRK update of the trailing tile
            float (*PJ)[65] = (ti == tj) ? Pi : Pj;
            const int ta = tid >> 4, tb = tid & 15;
            float acc[4][4] = {{0.f}};
            #pragma unroll
            for (int j = 0; j < 64; ++j) {
                float pa[4], pb[4];
                #pragma unroll
                for (int u = 0; u < 4; ++u) { pa[u] = Pi[ta * 4 + u][j]; pb[u] = PJ[tb * 4 + u][j]; }
                #pragma unroll
                for (int u = 0; u < 4; ++u)
                    #pragma unroll
                    for (int v = 0; v < 4; ++v) acc[u][v] += pa[u] * pb[v];
            }

            if (ti > tj) {
                #pragma unroll
                for (int u = 0; u < 4; ++u) {
                    float4* ptr = (float4*)&S[(size_t)(gi0 + ta * 4 + u) * QP + gj0 + tb * 4];
                    float4 cv = *ptr;
                    cv.x -= acc[u][0]; cv.y -= acc[u][1]; cv.z -= acc[u][2]; cv.w -= acc[u][3];
                    *ptr = cv;
                }
            } else {
                float nv[4][4];
                #pragma unroll
                for (int u = 0; u < 4; ++u) {
                    float4 cv = *(const float4*)&S[(size_t)(gi0 + ta * 4 + u) * QP + gj0 + tb * 4];
                    nv[u][0] = cv.x - acc[u][0]; nv[u][1] = cv.y - acc[u][1];
                    nv[u][2] = cv.z - acc[u][2]; nv[u][3] = cv.w - acc[u][3];
                }
                #pragma unroll
                for (int u = 0; u < 4; ++u)
                    #pragma unroll
                    for (int v = 0; v < 4; ++v) {
                        int gi = gi0 + ta * 4 + u, gj = gj0 + tb * 4 + v;
                        if (gi >= gj) S[(size_t)gi * QP + gj] = nv[u][v];
                    }
                if (ti == 0) {   // stage full updated tile for in-step factor
                    #pragma unroll
                    for (int u = 0; u < 4; ++u)
                        #pragma unroll
                        for (int v = 0; v < 4; ++v)
                            Pj[ta * 4 + u][tb * 4 + v] = nv[u][v];
                }
            }

            // block 0 == tile (0,0): factor next diagonal block in-step
            if (blk == 0) {
                __syncthreads();
                if (w == 0) {
                    float d[64];
                    #pragma unroll
                    for (int k = 0; k < 64; ++k) d[k] = Pj[lane][k];
                    chol64_store(d, S, invd, x + 64, lane);
                }
            }
        }
        gbar(bar, &bit, NB_CHOL);
    }

    // ---- epilogue: block 0 reduces logdet + combines scalars ----
    if (blk == 0) {
        float ld = 0.f;
        for (int i = tid; i < Q1; i += 256) ld += logf(S[(size_t)i * QP + i]);
        float* red = &Pi[0][0];
        __syncthreads();
        red[tid] = ld;
        __syncthreads();
        if (tid < 128) red[tid] += red[tid + 128];
        __syncthreads();
        if (tid < 64) red[tid] += red[tid + 64];
        __syncthreads();
        if (tid < 64) {
            float v = red[tid];
            #pragma unroll
            for (int o = 32; o; o >>= 1) v += __shfl_down(v, o, 64);
            if (tid == 0) {
                float L55 = S[(size_t)500 * QP + 500];
                float zz = KAPPA - L55 * L55;          // z^T z = v^T S^-1 v
                float rtr = ws[OFF_SC + 0];
                float la  = ws[OFF_SC + 1];
                float q0p = ws[OFF_SC + 2];
                float umu = q0p + zz;                  // u^T M^-1 u
                float loss2 = inv_se * rtr - inv_se * inv_se * umu;
                float logdetV = (float)N_PTS * logf(se)
                              + (float)Q0 * logf(sb0)
                              + (float)Q1 * logf(sb1)
                              + la + 2.f * v;
                out[0] = 0.5f * ((float)N_PTS * LOG_2PI + logdetV + loss2);
            }
        }
    }
}

// ------------------------------------------------------------------
extern "C" void kernel_launch(void* const* d_in, const int* in_sizes, int n_in,
                              void* d_out, int out_size, void* d_ws, size_t ws_size,
                              hipStream_t stream) {
    const float* yt = (const float*)d_in[0];
    const float* yp = (const float*)d_in[1];
    const int*   z0 = (const int*)d_in[2];
    const int*   z1 = (const int*)d_in[3];
    const float* se = (const float*)d_in[4];
    const float* sb = (const float*)d_in[5];
    float* ws  = (float*)d_ws;
    float* out = (float*)d_out;

    hipMemsetAsync(d_ws, 0, (size_t)ZERO_FLOATS * sizeof(float), stream);
    hipLaunchKernelGGL(k_pre, dim3(NB_PRE), dim3(256), 0, stream, yt, yp, z0, z1, ws);
    hipLaunchKernelGGL(k_chol, dim3(NB_CHOL), dim3(256), 0, stream, se, sb, ws, out);
}

// Round 12
// 406.549 us; speedup vs baseline: 1.0346x; 1.0279x over previous
//
#include <hip/hip_runtime.h>
#include <math.h>

// NLL of a Gaussian mixed model via double Schur complement / Woodbury.
// N=4096, factors Q0=1000, Q1=500. The N x N solve reduces to a 500x500
// (padded 512) Cholesky with the RHS appended as row 500 (augmented-row
// trick: z^T z = KAPPA - L[500][500]^2, logdet from diag of L).
// S is assembled SPARSELY by pair-enumeration over points grouped by z0.
// 3 launches total: memset + k_pre (scatter/scan/sort, 16 blocks) +
// k_chol (init + assemble + persistent blocked Cholesky, 28 blocks).
//
// ROUND-11 FIX: pin the 64-element register arrays (dreg/p/d) with empty
// asm volatile "+v" constraints after their load loops. R10 showed the
// compiler keeps p[64] live (VGPR=84) but SINKS the 64 dreg loads into the
// serial solve chain (minimal pressure), paying L2 latency ~64x per solve
// (96% stall, 35us/step). Pinning forces all 64 loads up front -> latency
// paid once. Requires (256,1) launch bounds (now ~170 VGPRs) from R10.

constexpr int N_PTS = 4096;
constexpr int Q0 = 1000;
constexpr int Q1 = 500;
constexpr int QP = 512;
constexpr float LOG_2PI = 1.8378770664093453f;
constexpr float KAPPA = 16384.f;   // > z^T z (~<= r^T r ~ 8200)

// ---- workspace layout (float offsets) ----
constexpr int OFF_C0   = 0;        // counts factor 0 [1000]
constexpr int OFF_C1   = 1024;     // counts factor 1 [500]
constexpr int OFF_U0   = 2048;     // residual sums factor 0 [1000]
constexpr int OFF_U1   = 3072;     // residual sums factor 1 [500]
constexpr int OFF_SC   = 3584;     // [0]=r^T r [1]=sum log a [2]=u0^T A^-1 u0
constexpr int OFF_BARP = 3616;     // k_pre barrier counter (own cacheline)
constexpr int OFF_BARC = 3648;     // k_chol barrier counter (own cacheline)
constexpr int ZERO_FLOATS = 3680;  // memset range
constexpr int OFF_INVD = 3712;     // inv diag of L [512] (fully written before read)
constexpr int OFF_OFFS = 4608;     // int[1024] exclusive offsets of sorted groups
constexpr int OFF_CURS = 5632;     // int[1024] scatter cursors
constexpr int OFF_SRT  = 6656;     // int[4096] z1 of points sorted by z0
constexpr int OFF_S    = 12288;    // S [QP][QP]
constexpr int NB_PRE   = 16;
constexpr int NB_CHOL  = 28;

__device__ __forceinline__ float readlane_f(float v, int l) {
    return __int_as_float(__builtin_amdgcn_readlane(__float_as_int(v), l));
}

// Pin all 64 elements into live VGPRs: compiler cannot sink/remat the
// producing loads past this point (rule #17 keep-alive idiom).
__device__ __forceinline__ void pin64(float (&d)[64]) {
    #pragma unroll
    for (int c = 0; c < 16; ++c)
        asm volatile("" : "+v"(d[4 * c + 0]), "+v"(d[4 * c + 1]),
                          "+v"(d[4 * c + 2]), "+v"(d[4 * c + 3]));
}

// grid barrier: RMW once to arrive, then poll with relaxed LOADs only.
__device__ __forceinline__ void gbar(unsigned* cnt, int* it, int nb) {
    __syncthreads();
    if (threadIdx.x == 0) {
        __threadfence();   // release
        __hip_atomic_fetch_add(cnt, 1u, __ATOMIC_RELAXED, __HIP_MEMORY_SCOPE_AGENT);
        unsigned target = (unsigned)nb * (unsigned)(++(*it));
        while (__hip_atomic_load(cnt, __ATOMIC_RELAXED, __HIP_MEMORY_SCOPE_AGENT) < target)
            __builtin_amdgcn_s_sleep(8);
        __threadfence();   // acquire
    }
    __syncthreads();
}

// ------------------------------------------------------------------
// k_pre: scatter -> prefix scan -> counting sort (16 blocks)
// ------------------------------------------------------------------
__global__ __launch_bounds__(256) void k_pre(const float* __restrict__ yt,
                                             const float* __restrict__ yp,
                                             const int* __restrict__ z0,
                                             const int* __restrict__ z1,
                                             float* __restrict__ ws) {
    unsigned* bar = (unsigned*)(ws + OFF_BARP);
    int it = 0;
    const int tid = threadIdx.x;
    const int i = blockIdx.x * 256 + tid;     // exactly 4096 threads

    // phase A: scatter
    float r = yt[i] - yp[i];
    int i0 = z0[i];
    int i1 = z1[i];
    atomicAdd(&ws[OFF_C0 + i0], 1.0f);
    atomicAdd(&ws[OFF_C1 + i1], 1.0f);
    atomicAdd(&ws[OFF_U0 + i0], r);
    atomicAdd(&ws[OFF_U1 + i1], r);
    float r2 = r * r;
    #pragma unroll
    for (int off = 32; off; off >>= 1) r2 += __shfl_down(r2, off, 64);
    if ((tid & 63) == 0) atomicAdd(&ws[OFF_SC + 0], r2);

    gbar(bar, &it, NB_PRE);

    // phase B: block 0 scans C0 -> OFFS/CURS (1024 entries, 4 per thread)
    if (blockIdx.x == 0) {
        __shared__ int sums[256];
        int b4 = tid * 4;
        int v[4], tot = 0;
        #pragma unroll
        for (int k = 0; k < 4; ++k) {
            v[k] = (b4 + k < Q0) ? (int)ws[OFF_C0 + b4 + k] : 0;
            tot += v[k];
        }
        sums[tid] = tot;
        __syncthreads();
        for (int off = 1; off < 256; off <<= 1) {
            int a = (tid >= off) ? sums[tid - off] : 0;
            __syncthreads();
            sums[tid] += a;
            __syncthreads();
        }
        int run = sums[tid] - tot;    // exclusive base
        int* offs = (int*)(ws + OFF_OFFS);
        int* curs = (int*)(ws + OFF_CURS);
        #pragma unroll
        for (int k = 0; k < 4; ++k) {
            offs[b4 + k] = run;
            curs[b4 + k] = run;
            run += v[k];
        }
    }

    gbar(bar, &it, NB_PRE);

    // phase C: counting-sort scatter of z1 grouped by z0
    int slot = atomicAdd(&((int*)(ws + OFF_CURS))[i0], 1);
    ((int*)(ws + OFF_SRT))[slot] = i1;
}

// ------------------------------------------------------------------
// register Cholesky of a 64x64 block (lane = row), masked store,
// plus reciprocal-diagonal store. d must be pinned by caller.
// ------------------------------------------------------------------
__device__ __forceinline__ void chol64_store(float (&d)[64], float* S, float* invd,
                                             int base, int lane) {
    float myinv = 0.f;
    #pragma unroll
    for (int j = 0; j < 64; ++j) {
        float diag = readlane_f(d[j], j);
        float rs = rsqrtf(diag);
        if (lane == j) myinv = rs;
        d[j] *= rs;
        float lj = d[j];
        #pragma unroll
        for (int k = j + 1; k < 64; ++k)
            d[k] = fmaf(-lj, readlane_f(lj, k), d[k]);
    }
    invd[base + lane] = myinv;     // 1/L[j][j], exact rsqrt approx (<=1ulp)
    float* wr = S + (size_t)(base + lane) * QP + base;
    #pragma unroll
    for (int c = 0; c < 16; ++c) {
        float4 v;
        v.x = (4 * c + 0 <= lane) ? d[4 * c + 0] : 0.f;
        v.y = (4 * c + 1 <= lane) ? d[4 * c + 1] : 0.f;
        v.z = (4 * c + 2 <= lane) ? d[4 * c + 2] : 0.f;
        v.w = (4 * c + 3 <= lane) ? d[4 * c + 3] : 0.f;
        *reinterpret_cast<float4*>(wr + 4 * c) = v;
    }
}

// triangular solve of 64 panel rows (lane = row) against factored D at x;
// division-free (uses invd); result into LDS tile. dreg/p pinned so all
// 128 loads issue up front (no sinking into the serial chain).
__device__ __forceinline__ void solve_tile(const float* S, const float* invd,
                                           int x, int g0, float (*out)[65], int lane) {
    float invv = invd[x + lane];
    float dreg[64], p[64];
    const float* dr = S + (size_t)(x + lane) * QP + x;
    const float* pr = S + (size_t)(g0 + lane) * QP + x;
    #pragma unroll
    for (int c = 0; c < 16; ++c) {
        float4 v = *reinterpret_cast<const float4*>(dr + 4 * c);
        dreg[4 * c] = v.x; dreg[4 * c + 1] = v.y; dreg[4 * c + 2] = v.z; dreg[4 * c + 3] = v.w;
        float4 q = *reinterpret_cast<const float4*>(pr + 4 * c);
        p[4 * c] = q.x; p[4 * c + 1] = q.y; p[4 * c + 2] = q.z; p[4 * c + 3] = q.w;
    }
    pin64(dreg);
    pin64(p);
    #pragma unroll
    for (int j = 0; j < 64; ++j) {
        float pj = p[j] * readlane_f(invv, j);
        p[j] = pj;
        #pragma unroll
        for (int k = j + 1; k < 64; ++k)
            p[k] = fmaf(-pj, readlane_f(dreg[j], k), p[k]);
    }
    #pragma unroll
    for (int k = 0; k < 64; ++k) out[lane][k] = p[k];
}

// ------------------------------------------------------------------
// k_chol: init S + sparse assembly + persistent blocked Cholesky + epilogue
// ------------------------------------------------------------------
__global__ __launch_bounds__(256, 1) void k_chol(const float* __restrict__ sig2e,
                                                 const float* __restrict__ sig2bs,
                                                 float* __restrict__ ws,
                                                 float* __restrict__ out) {
    float* S = ws + OFF_S;
    float* invd = ws + OFF_INVD;
    unsigned* bar = (unsigned*)(ws + OFF_BARC);
    const int tid = threadIdx.x;
    const int lane = tid & 63;
    const int w = tid >> 6;
    const int blk = blockIdx.x;
    __shared__ float Pi[64][65];
    __shared__ float Pj[64][65];
    int bit = 0;

    const float se = sig2e[0], sb0 = sig2bs[0], sb1 = sig2bs[1];
    const float inv_se = 1.f / se, inv_sb0 = 1.f / sb0, inv_sb1 = 1.f / sb1;

    // ---- phase 0a: init S base (diag, rhs row 500, identity padding) ----
    {
        const float* C1w = ws + OFF_C1;
        const float* U1w = ws + OFF_U1;
        for (int e = blk * 256 + tid; e < QP * QP / 4; e += NB_CHOL * 256) {
            int i = e >> 7;
            int j0 = (e & 127) << 2;
            float4 v;
            float* el = &v.x;
            #pragma unroll
            for (int t = 0; t < 4; ++t) {
                int j = j0 + t;
                float x = 0.f;
                if (i == 500)      x = (j < Q1) ? U1w[j] : ((j == 500) ? KAPPA : 0.f);
                else if (i == j)   x = (i < Q1) ? (inv_sb1 + C1w[i] * inv_se) : 1.f;
                el[t] = x;
            }
            *reinterpret_cast<float4*>(S + (size_t)i * QP + j0) = v;
        }
    }
    gbar(bar, &bit, NB_CHOL);

    // ---- phase 0b: sparse pair assembly (thread per group g0) ----
    if (blk < 4) {   // 4*256 = 1024 >= Q0
        int g = blk * 256 + tid;
        const bool act = g < Q0;
        const int* offs = (const int*)(ws + OFF_OFFS);
        const int* srt  = (const int*)(ws + OFF_SRT);
        float la = 0.f, q0 = 0.f, wu = 0.f, cg = 0.f;
        if (act) {
            cg = ws[OFF_C0 + g];
            float a  = inv_sb0 + cg * inv_se;
            float u0 = ws[OFF_U0 + g];
            wu = u0 / a;
            la = logf(a);
            q0 = u0 * wu;
        }
        // wave-reduce the two same-address scalar atomics (1000 RMWs -> 16)
        float laR = la, q0R = q0;
        #pragma unroll
        for (int off = 32; off; off >>= 1) {
            laR += __shfl_down(laR, off, 64);
            q0R += __shfl_down(q0R, off, 64);
        }
        if (lane == 0) {
            atomicAdd(&ws[OFF_SC + 1], laR);
            atomicAdd(&ws[OFF_SC + 2], q0R);
        }
        if (act) {
            float a  = inv_sb0 + cg * inv_se;
            int beg = offs[g];
            int cnt = (int)cg;
            float coef = -inv_se * inv_se / a;
            float rhsv = -inv_se * wu;
            for (int ia = beg; ia < beg + cnt; ++ia) {
                int ca = srt[ia];
                atomicAdd(&S[(size_t)500 * QP + ca], rhsv);
                for (int ib = beg; ib < beg + cnt; ++ib) {
                    int cb = srt[ib];
                    if (ca >= cb) atomicAdd(&S[(size_t)ca * QP + cb], coef);
                }
            }
        }
    }
    gbar(bar, &bit, NB_CHOL);

    // ---- phase 0c: block 0 factors D0 ----
    if (blk == 0 && w == 0) {
        float d[64];
        const float* row = S + (size_t)lane * QP;
        #pragma unroll
        for (int c = 0; c < 16; ++c) {
            float4 v = *reinterpret_cast<const float4*>(row + 4 * c);
            d[4 * c] = v.x; d[4 * c + 1] = v.y; d[4 * c + 2] = v.z; d[4 * c + 3] = v.w;
        }
        pin64(d);
        chol64_store(d, S, invd, 0, lane);
    }
    gbar(bar, &bit, NB_CHOL);

    // ---- main factorization: 7 steps ----
    for (int s = 0; s < 7; ++s) {
        const int x = 64 * s;
        const int T = 7 - s;
        const int nt = T * (T + 1) / 2;
        if (blk < nt) {
            int ti = 0;
            while ((ti + 1) * (ti + 2) / 2 <= blk) ++ti;
            int tj = blk - ti * (ti + 1) / 2;
            const int gi0 = x + 64 + 64 * ti;
            const int gj0 = x + 64 + 64 * tj;

            // redundant panel solves, straight into LDS
            if (w == 0)                     solve_tile(S, invd, x, gi0, Pi, lane);
            else if (w == 1 && ti != tj)    solve_tile(S, invd, x, gj0, Pj, lane);
            __syncthreads();

            // SYRK update of the trailing tile
            float (*PJ)[65] = (ti == tj) ? Pi : Pj;
            const int ta = tid >> 4, tb = tid & 15;
            float acc[4][4] = {{0.f}};
            #pragma unroll
            for (int j = 0; j < 64; ++j) {
                float pa[4], pb[4];
                #pragma unroll
                for (int u = 0; u < 4; ++u) { pa[u] = Pi[ta * 4 + u][j]; pb[u] = PJ[tb * 4 + u][j]; }
                #pragma unroll
                for (int u = 0; u < 4; ++u)
                    #pragma unroll
                    for (int v = 0; v < 4; ++v) acc[u][v] += pa[u] * pb[v];
            }

            if (ti > tj) {
                #pragma unroll
                for (int u = 0; u < 4; ++u) {
                    float4* ptr = (float4*)&S[(size_t)(gi0 + ta * 4 + u) * QP + gj0 + tb * 4];
                    float4 cv = *ptr;
                    cv.x -= acc[u][0]; cv.y -= acc[u][1]; cv.z -= acc[u][2]; cv.w -= acc[u][3];
                    *ptr = cv;
                }
            } else {
                float nv[4][4];
                #pragma unroll
                for (int u = 0; u < 4; ++u) {
                    float4 cv = *(const float4*)&S[(size_t)(gi0 + ta * 4 + u) * QP + gj0 + tb * 4];
                    nv[u][0] = cv.x - acc[u][0]; nv[u][1] = cv.y - acc[u][1];
                    nv[u][2] = cv.z - acc[u][2]; nv[u][3] = cv.w - acc[u][3];
                }
                #pragma unroll
                for (int u = 0; u < 4; ++u)
                    #pragma unroll
                    for (int v = 0; v < 4; ++v) {
                        int gi = gi0 + ta * 4 + u, gj = gj0 + tb * 4 + v;
                        if (gi >= gj) S[(size_t)gi * QP + gj] = nv[u][v];
                    }
                if (ti == 0) {   // stage full updated tile for in-step factor
                    #pragma unroll
                    for (int u = 0; u < 4; ++u)
                        #pragma unroll
                        for (int v = 0; v < 4; ++v)
                            Pj[ta * 4 + u][tb * 4 + v] = nv[u][v];
                }
            }

            // block 0 == tile (0,0): factor next diagonal block in-step
            if (blk == 0) {
                __syncthreads();
                if (w == 0) {
                    float d[64];
                    #pragma unroll
                    for (int k = 0; k < 64; ++k) d[k] = Pj[lane][k];
                    pin64(d);
                    chol64_store(d, S, invd, x + 64, lane);
                }
            }
        }
        gbar(bar, &bit, NB_CHOL);
    }

    // ---- epilogue: block 0 reduces logdet + combines scalars ----
    if (blk == 0) {
        float ld = 0.f;
        for (int i = tid; i < Q1; i += 256) ld += logf(S[(size_t)i * QP + i]);
        float* red = &Pi[0][0];
        __syncthreads();
        red[tid] = ld;
        __syncthreads();
        if (tid < 128) red[tid] += red[tid + 128];
        __syncthreads();
        if (tid < 64) red[tid] += red[tid + 64];
        __syncthreads();
        if (tid < 64) {
            float v = red[tid];
            #pragma unroll
            for (int o = 32; o; o >>= 1) v += __shfl_down(v, o, 64);
            if (tid == 0) {
                float L55 = S[(size_t)500 * QP + 500];
                float zz = KAPPA - L55 * L55;          // z^T z = v^T S^-1 v
                float rtr = ws[OFF_SC + 0];
                float la  = ws[OFF_SC + 1];
                float q0p = ws[OFF_SC + 2];
                float umu = q0p + zz;                  // u^T M^-1 u
                float loss2 = inv_se * rtr - inv_se * inv_se * umu;
                float logdetV = (float)N_PTS * logf(se)
                              + (float)Q0 * logf(sb0)
                              + (float)Q1 * logf(sb1)
                              + la + 2.f * v;
                out[0] = 0.5f * ((float)N_PTS * LOG_2PI + logdetV + loss2);
            }
        }
    }
}

// ------------------------------------------------------------------
extern "C" void kernel_launch(void* const* d_in, const int* in_sizes, int n_in,
                              void* d_out, int out_size, void* d_ws, size_t ws_size,
                              hipStream_t stream) {
    const float* yt = (const float*)d_in[0];
    const float* yp = (const float*)d_in[1];
    const int*   z0 = (const int*)d_in[2];
    const int*   z1 = (const int*)d_in[3];
    const float* se = (const float*)d_in[4];
    const float* sb = (const float*)d_in[5];
    float* ws  = (float*)d_ws;
    float* out = (float*)d_out;

    hipMemsetAsync(d_ws, 0, (size_t)ZERO_FLOATS * sizeof(float), stream);
    hipLaunchKernelGGL(k_pre, dim3(NB_PRE), dim3(256), 0, stream, yt, yp, z0, z1, ws);
    hipLaunchKernelGGL(k_chol, dim3(NB_CHOL), dim3(256), 0, stream, se, sb, ws, out);
}